// Round 3
// baseline (504.311 us; speedup 1.0000x reference)
//
#include <hip/hip_runtime.h>
#include <math.h>

#define NE 22   // electrons
#define NA 11   // atoms
#define HD 8    // HID
#define H2 16   // 2*HID
#define QN 22   // QNUM
#define NL 6    // layers
#define CPAD 12 // atom conv position slots (11 + 1 pad)
#define CSTR 17 // conv row stride in floats (breaks pow2 bank pattern)

struct QCS { float c[QN]; float s[QN]; };

// wave-uniform broadcast of a lane-distributed register (lane idx is compile-time)
#define RL(v, l) __uint_as_float(__builtin_amdgcn_readlane(__float_as_uint(v), (l)))

__device__ __forceinline__ float block_reduce_sum(float v, float* red, int tid) {
  red[tid] = v;
  __syncthreads();
  for (int off = 128; off > 0; off >>= 1) {
    if (tid < off) red[tid] += red[tid + off];
    __syncthreads();
  }
  float s = red[0];
  __syncthreads();
  return s;
}

__device__ __forceinline__ void ln_vec(const float* x, int n, const float* __restrict__ g,
                                       const float* __restrict__ bb, float* o) {
  float m = 0.f;
  for (int i = 0; i < n; i++) m += x[i];
  m /= (float)n;
  float v = 0.f;
  for (int i = 0; i < n; i++) { float d = x[i] - m; v += d * d; }
  v /= (float)n;
  float is = 1.0f / sqrtf(v + 1e-5f);
  for (int i = 0; i < n; i++) o[i] = (x[i] - m) * is * g[i] + bb[i];
}

__global__ __launch_bounds__(256) void small_net_kernel(
    const float* __restrict__ pos_a, const int* __restrict__ ix_a,
    const int* __restrict__ pos_ix, const int* __restrict__ atom_ix,
    const float* __restrict__ rpos_w, const float* __restrict__ emb_w,
    const float* __restrict__ emb_b,
    const float* __restrict__ Wq, const float* __restrict__ bq,
    const float* __restrict__ Wk, const float* __restrict__ bk,
    const float* __restrict__ Wv, const float* __restrict__ bv,
    const float* __restrict__ Wo, const float* __restrict__ bo,
    const float* __restrict__ W1, const float* __restrict__ b1,
    const float* __restrict__ W2, const float* __restrict__ b2,
    const float* __restrict__ ln1_g, const float* __restrict__ ln1_b,
    const float* __restrict__ ln2_g, const float* __restrict__ ln2_b,
    const float* __restrict__ Wi, const float* __restrict__ bi,
    const float* __restrict__ ni_g, const float* __restrict__ ni_b,
    const float* __restrict__ conv_a_w, const float* __restrict__ conv_e_w,
    float* __restrict__ xf_out)
{
  const int tid = threadIdx.x;
  const int lane = tid & 63;
  const int b = tid / NA;
  const int a = tid % NA;
  const bool act = (tid < NE * NA);

  __shared__ __align__(16) float s_seq[NE][NA][HD];
  __shared__ __align__(16) float s_k[NE][NA][HD];
  __shared__ __align__(16) float s_v[NE][NA][HD];
  __shared__ float s_pos_e[NE][3];
  __shared__ float s_amp[NA];
  __shared__ float s_er[NE][NA];
  __shared__ float s_red[256];
  __shared__ float s_scal[8];     // 0: amp_ae, 1: bias_ae, 4: amp_r2
  __shared__ float s_aeinv[HD];
  __shared__ float convA[NE * CPAD * CSTR];
  __shared__ float convB[NE * CPAD * CSTR];
  __shared__ float s_y[NE][H2];
  __shared__ float s_ampr[NE];
  __shared__ float s_eA[24 * CSTR];
  __shared__ float s_eB[24 * CSTR];
  __shared__ float s_y2[H2];
  __shared__ float s_cewt[32 * H2]; // conv_e_w transposed: [(i*2+k)][o]

  // ---- lane-distributed weights (coalesced global loads, ALL threads) ----
  float cwr[8], wir[2];
  #pragma unroll
  for (int j = 0; j < 8; j++) cwr[j] = conv_a_w[j * 64 + lane];
  #pragma unroll
  for (int j = 0; j < 2; j++) wir[j] = Wi[j * 64 + lane];

  // transposed electron-conv weights into LDS (stride-1 over o -> conflict-free)
  for (int s = tid; s < 512; s += 256) {
    int o = s >> 5, i = (s >> 1) & 15, k = s & 1;
    s_cewt[(i * 2 + k) * 16 + o] = conv_e_w[s];
  }

  // ---- small scattered inputs ----
  if (tid < NE) {
    int p = pos_ix[tid], am = atom_ix[tid];
    for (int j = 0; j < 3; j++) s_pos_e[tid][j] = rpos_w[p * 3 + j] + pos_a[am * 3 + j];
  }
  if (tid < NA) s_amp[tid] = (float)ix_a[tid];
  __syncthreads();

  float rae = 0.f;
  if (act) {
    float d0 = s_pos_e[b][0] - pos_a[a * 3 + 0];
    float d1 = s_pos_e[b][1] - pos_a[a * 3 + 1];
    float d2 = s_pos_e[b][2] - pos_a[a * 3 + 2];
    rae = sqrtf(d0 * d0 + d1 * d1 + d2 * d2);
    float in4[4] = { d0, d1, d2, rae };
    #pragma unroll
    for (int h = 0; h < HD; h++) {
      float s = emb_b[h];               // uniform -> s_load
      #pragma unroll
      for (int j = 0; j < 4; j++) s += in4[j] * emb_w[h * 4 + j];
      s_seq[b][a][h] = s;
    }
  }
  {
    float sum = block_reduce_sum(act ? rae : 0.f, s_red, tid);
    float mean = sum / (float)(NE * NA);
    float d = act ? (rae - mean) : 0.f;
    float ss = block_reduce_sum(d * d, s_red, tid);
    if (tid == 0) { s_scal[0] = sqrtf(ss / (float)(NE * NA - 1)); s_scal[1] = mean; }
  }
  __syncthreads();

  // ---- transformer layers: weights via readlane broadcast ----
  const float iscale = 0.35355339059327373f; // 1/sqrt(8)
  for (int l = 0; l < NL; l++) {
    float wr[12];
    wr[0] = Wq[l * 64 + lane];
    wr[1] = Wk[l * 64 + lane];
    wr[2] = Wv[l * 64 + lane];
    wr[3] = Wo[l * 64 + lane];
    #pragma unroll
    for (int j = 0; j < 4; j++) wr[4 + j] = W1[l * 256 + j * 64 + lane];
    #pragma unroll
    for (int j = 0; j < 4; j++) wr[8 + j] = W2[l * 256 + j * 64 + lane];

    float xv[HD], qq[HD];
    if (act) {
      float amp = s_amp[a];
      float4 sq0 = *(const float4*)&s_seq[b][a][0];
      float4 sq1 = *(const float4*)&s_seq[b][a][4];
      xv[0] = amp * sq0.x; xv[1] = amp * sq0.y; xv[2] = amp * sq0.z; xv[3] = amp * sq0.w;
      xv[4] = amp * sq1.x; xv[5] = amp * sq1.y; xv[6] = amp * sq1.z; xv[7] = amp * sq1.w;
      float kk[HD], vv[HD];
      #pragma unroll
      for (int h = 0; h < HD; h++) {
        float q_ = bq[l * HD + h], k_ = bk[l * HD + h], v_ = bv[l * HD + h];
        #pragma unroll
        for (int h2 = 0; h2 < HD; h2++) {
          q_ += xv[h2] * RL(wr[0], h * 8 + h2);
          k_ += xv[h2] * RL(wr[1], h * 8 + h2);
          v_ += xv[h2] * RL(wr[2], h * 8 + h2);
        }
        qq[h] = q_; kk[h] = k_; vv[h] = v_;
      }
      *(float4*)&s_k[b][a][0] = make_float4(kk[0], kk[1], kk[2], kk[3]);
      *(float4*)&s_k[b][a][4] = make_float4(kk[4], kk[5], kk[6], kk[7]);
      *(float4*)&s_v[b][a][0] = make_float4(vv[0], vv[1], vv[2], vv[3]);
      *(float4*)&s_v[b][a][4] = make_float4(vv[4], vv[5], vv[6], vv[7]);
    }
    __syncthreads();
    if (act) {
      float sc[NA];
      float mx = -1e30f;
      #pragma unroll
      for (int ka = 0; ka < NA; ka++) {
        float4 k0 = *(const float4*)&s_k[b][ka][0];
        float4 k1 = *(const float4*)&s_k[b][ka][4];
        float s = qq[0]*k0.x + qq[1]*k0.y + qq[2]*k0.z + qq[3]*k0.w
                + qq[4]*k1.x + qq[5]*k1.y + qq[6]*k1.z + qq[7]*k1.w;
        s *= iscale;
        sc[ka] = s;
        mx = fmaxf(mx, s);
      }
      float den = 0.f;
      #pragma unroll
      for (int ka = 0; ka < NA; ka++) { sc[ka] = expf(sc[ka] - mx); den += sc[ka]; }
      float inv_den = 1.0f / den;
      float av[HD];
      #pragma unroll
      for (int h = 0; h < HD; h++) av[h] = 0.f;
      #pragma unroll
      for (int ka = 0; ka < NA; ka++) {
        float4 v0 = *(const float4*)&s_v[b][ka][0];
        float4 v1 = *(const float4*)&s_v[b][ka][4];
        float p = sc[ka];
        av[0] += p * v0.x; av[1] += p * v0.y; av[2] += p * v0.z; av[3] += p * v0.w;
        av[4] += p * v1.x; av[5] += p * v1.y; av[6] += p * v1.z; av[7] += p * v1.w;
      }
      #pragma unroll
      for (int h = 0; h < HD; h++) av[h] *= inv_den;
      float xr[HD], xn[HD];
      #pragma unroll
      for (int h = 0; h < HD; h++) {
        float t = bo[l * HD + h];
        #pragma unroll
        for (int h2 = 0; h2 < HD; h2++) t += av[h2] * RL(wr[3], h * 8 + h2);
        xr[h] = xv[h] + t;
      }
      ln_vec(xr, HD, ln1_g + l * HD, ln1_b + l * HD, xn);
      float f2[HD];
      #pragma unroll
      for (int h = 0; h < HD; h++) f2[h] = b2[l * HD + h];
      #pragma unroll
      for (int o = 0; o < 32; o++) {
        float t = b1[l * 32 + o];
        #pragma unroll
        for (int h = 0; h < HD; h++) t += xn[h] * RL(wr[4 + ((o * 8 + h) >> 6)], (o * 8 + h) & 63);
        t = fmaxf(t, 0.f);
        #pragma unroll
        for (int h = 0; h < HD; h++) f2[h] += t * RL(wr[8 + ((h * 32 + o) >> 6)], (h * 32 + o) & 63);
      }
      #pragma unroll
      for (int h = 0; h < HD; h++) xr[h] = xn[h] + f2[h];
      ln_vec(xr, HD, ln2_g + l * HD, ln2_b + l * HD, xn);
      *(float4*)&s_seq[b][a][0] = make_float4(xn[0], xn[1], xn[2], xn[3]);
      *(float4*)&s_seq[b][a][4] = make_float4(xn[4], xn[5], xn[6], xn[7]);
    }
    __syncthreads();
  }

  // ---- ae_inv last row ----
  if (tid == 0) {
    double M[4][8];
    for (int i = 0; i < 4; i++)
      for (int j = 0; j < 4; j++) {
        double s = 0.0;
        for (int h = 0; h < HD; h++) s += (double)emb_w[h * 4 + i] * (double)emb_w[h * 4 + j];
        M[i][j] = s;
        M[i][4 + j] = (i == j) ? 1.0 : 0.0;
      }
    for (int c = 0; c < 4; c++) {
      int piv = c;
      for (int r2 = c + 1; r2 < 4; r2++) if (fabs(M[r2][c]) > fabs(M[piv][c])) piv = r2;
      if (piv != c) for (int j = 0; j < 8; j++) { double t = M[c][j]; M[c][j] = M[piv][j]; M[piv][j] = t; }
      double dd = M[c][c];
      for (int j = 0; j < 8; j++) M[c][j] /= dd;
      for (int r2 = 0; r2 < 4; r2++) if (r2 != c) {
        double f = M[r2][c];
        for (int j = 0; j < 8; j++) M[r2][j] -= f * M[c][j];
      }
    }
    for (int h = 0; h < HD; h++) {
      double s = 0.0;
      for (int j = 0; j < 4; j++) s += M[3][4 + j] * (double)emb_w[h * 4 + j];
      s_aeinv[h] = (float)s;
    }
  }
  __syncthreads();

  // ---- r projection + normalization + exp(-r) ----
  float rv = 0.f;
  if (act) {
    #pragma unroll
    for (int h = 0; h < HD; h++) rv += s_aeinv[h] * s_seq[b][a][h];
  }
  {
    float sum = block_reduce_sum(act ? rv : 0.f, s_red, tid);
    float rm = sum / (float)(NE * NA);
    float d = act ? (rv - rm) : 0.f;
    float ss = block_reduce_sum(d * d, s_red, tid);
    float rs = sqrtf(ss / (float)(NE * NA - 1));
    if (act) {
      float rr = s_scal[0] * (rv - rm) / rs + s_scal[1];
      s_er[b][a] = expf(-rr);
    }
  }
  __syncthreads();

  // ---- Wi projection into conv buffer [bb][pos][chan] (stride CSTR) ----
  if (act) {
    float e2 = s_er[b][a] * s_amp[a];
    float4 sq0 = *(const float4*)&s_seq[b][a][0];
    float4 sq1 = *(const float4*)&s_seq[b][a][4];
    float tv[HD] = { e2*sq0.x, e2*sq0.y, e2*sq0.z, e2*sq0.w,
                     e2*sq1.x, e2*sq1.y, e2*sq1.z, e2*sq1.w };
    #pragma unroll
    for (int o = 0; o < H2; o++) {
      float s = bi[o];
      #pragma unroll
      for (int h = 0; h < HD; h++) s += tv[h] * RL(wir[(o * 8 + h) >> 6], (o * 8 + h) & 63);
      convA[(b * CPAD + a) * CSTR + o] = s;
    }
  }
  // zero pad row 11
  for (int z = tid; z < NE * H2; z += 256)
    convA[((z >> 4) * CPAD + 11) * CSTR + (z & 15)] = 0.f;
  __syncthreads();

  // ---- y (mean over atoms), amp_r ----
  for (int idx = tid; idx < NE * H2; idx += 256) {
    int bb = idx >> 4, o = idx & 15;
    float s = 0.f;
    for (int a2 = 0; a2 < NA; a2++) s += convA[(bb * CPAD + a2) * CSTR + o];
    s_y[bb][o] = s / (float)NA;
  }
  if (tid < NE) {
    float s = 0.f;
    for (int a2 = 0; a2 < NA; a2++) s += s_er[tid][a2];
    s_ampr[tid] = s / (float)NA;
  }
  __syncthreads();

  // ---- atom conv pyramid (weights via readlane, 16 chans/thread) ----
  float* pin = convA;
  float* pout = convB;
  int L = NA;
  for (int it = 0; it < 6; it++) {
    int Lo = (L - 1) / 2 + 1;
    for (int pos = tid; pos < NE * Lo; pos += 256) {
      int bb = pos / Lo, j = pos - bb * Lo;
      const float* r0 = pin + (bb * CPAD + 2 * j) * CSTR;
      const float* r1 = r0 + CSTR;
      float x0[16], x1[16];
      #pragma unroll
      for (int i = 0; i < 16; i++) { x0[i] = r0[i]; x1[i] = r1[i]; }
      float* wrow = pout + (bb * CPAD + j) * CSTR;
      #pragma unroll
      for (int o = 0; o < 16; o++) {
        float acc = 0.f;
        #pragma unroll
        for (int i = 0; i < 16; i++) {
          acc += x0[i] * RL(cwr[((o * 16 + i) * 2) >> 6], ((o * 16 + i) * 2) & 63)
               + x1[i] * RL(cwr[((o * 16 + i) * 2 + 1) >> 6], ((o * 16 + i) * 2 + 1) & 63);
        }
        wrow[o] = acc;
      }
    }
    for (int z = tid; z < NE * H2; z += 256)
      pout[((z >> 4) * CPAD + Lo) * CSTR + (z & 15)] = 0.f;
    __syncthreads();
    float* t = pin; pin = pout; pout = t;
    L = Lo;
  }

  // ---- per-electron LN, amp_r scaling -> electron buffer [pos][chan] ----
  if (tid < NE) {
    float t[H2], oo[H2];
    #pragma unroll
    for (int o = 0; o < H2; o++) t[o] = s_y[tid][o] + pin[(tid * CPAD) * CSTR + o];
    ln_vec(t, H2, ni_g, ni_b, oo);
    float ar = s_ampr[tid];
    #pragma unroll
    for (int o = 0; o < H2; o++) s_eA[tid * CSTR + o] = ar * oo[o];
  }
  if (tid < H2) s_eA[NE * CSTR + tid] = 0.f;   // pad row 22
  __syncthreads();
  if (tid < H2) {
    float s = 0.f;
    for (int bb = 0; bb < NE; bb++) s += s_eA[bb * CSTR + tid];
    s_y2[tid] = s / (float)NE;
  }
  if (tid == 0) {
    float s = 0.f;
    for (int bb = 0; bb < NE; bb++) s += s_ampr[bb];
    s_scal[4] = s / (float)NE;   // amp_r2
  }
  __syncthreads();

  // ---- electron conv pyramid (transposed weights in LDS) ----
  float* pinE = s_eA;
  float* poutE = s_eB;
  L = NE;
  for (int it = 0; it < 11; it++) {
    int Lo = (L - 1) / 2 + 1;
    for (int idx = tid; idx < Lo * H2; idx += 256) {
      int j = idx >> 4, o = idx & 15;
      const float* r0 = pinE + (2 * j) * CSTR;
      const float* r1 = r0 + CSTR;
      float acc = 0.f;
      #pragma unroll
      for (int i = 0; i < 16; i++)
        acc += r0[i] * s_cewt[(i * 2) * 16 + o] + r1[i] * s_cewt[(i * 2 + 1) * 16 + o];
      poutE[j * CSTR + o] = acc;
    }
    if (tid < H2) poutE[Lo * CSTR + tid] = 0.f;
    __syncthreads();
    float* t = pinE; pinE = poutE; poutE = t;
    L = Lo;
  }

  // ---- final LN + amp_r2 scale -> xf[16] ----
  if (tid == 0) {
    float t[H2], oo[H2];
    for (int o = 0; o < H2; o++) t[o] = s_y2[o] + pinE[o];
    ln_vec(t, H2, ni_g, ni_b, oo);
    float a2 = s_scal[4];
    for (int o = 0; o < H2; o++) xf_out[o] = a2 * oo[o];
  }
}

// ---- big memory-bound output projection: psi + 2^(Q/2) * bos ----
// fully coalesced: each wave reads its 64x16-float tile as 4 contiguous 1-KiB loads,
// quad-shuffle reduces the 4-lane partial dots.
__global__ __launch_bounds__(256) void psi_kernel(
    const float* __restrict__ Wout, const float* __restrict__ bout,
    const float* __restrict__ xf, float* __restrict__ out, QCS cs, int n)
{
  __shared__ float s_xf[H2];
  if (threadIdx.x < H2) s_xf[threadIdx.x] = xf[threadIdx.x];
  __syncthreads();
  int lane = threadIdx.x & 63;
  int waveBase = blockIdx.x * 256 + (threadIdx.x & ~63);
  if (waveBase >= n) return;
  const float4* W4 = (const float4*)Wout + (size_t)waveBase * 4;
  int q = lane & 3;
  float4 xq = make_float4(s_xf[q * 4], s_xf[q * 4 + 1], s_xf[q * 4 + 2], s_xf[q * 4 + 3]);
  #pragma unroll
  for (int j = 0; j < 4; j++) {
    float4 w = W4[j * 64 + lane];                 // coalesced 1 KiB / wave-instr
    float p = w.x * xq.x + w.y * xq.y + w.z * xq.z + w.w * xq.w;
    p += __shfl_xor(p, 1, 64);
    p += __shfl_xor(p, 2, 64);
    if (q == 0) {
      int row = waveBase + j * 16 + (lane >> 2);
      float acc = bout[row] + p;
      unsigned int ii = (unsigned int)row;
      float pr = (float)(1 << (QN / 2));          // 2048
      #pragma unroll
      for (int qb = 0; qb < QN; qb++)
        pr *= ((ii >> (QN - 1 - qb)) & 1u) ? cs.s[qb] : cs.c[qb];
      out[row] = acc + pr;
    }
  }
}

extern "C" void kernel_launch(void* const* d_in, const int* in_sizes, int n_in,
                              void* d_out, int out_size, void* d_ws, size_t ws_size,
                              hipStream_t stream) {
  const float* pos_a   = (const float*)d_in[0];
  const int*   ix_a    = (const int*)d_in[1];
  const int*   pos_ix  = (const int*)d_in[2];
  const int*   atom_ix = (const int*)d_in[3];
  const float* rpos_w  = (const float*)d_in[4];
  const float* emb_w   = (const float*)d_in[5];
  const float* emb_b   = (const float*)d_in[6];
  const float* Wq = (const float*)d_in[7];   const float* bq = (const float*)d_in[8];
  const float* Wk = (const float*)d_in[9];   const float* bk = (const float*)d_in[10];
  const float* Wv = (const float*)d_in[11];  const float* bv = (const float*)d_in[12];
  const float* Wo = (const float*)d_in[13];  const float* bo = (const float*)d_in[14];
  const float* W1 = (const float*)d_in[15];  const float* b1 = (const float*)d_in[16];
  const float* W2 = (const float*)d_in[17];  const float* b2 = (const float*)d_in[18];
  const float* ln1_g = (const float*)d_in[19]; const float* ln1_b = (const float*)d_in[20];
  const float* ln2_g = (const float*)d_in[21]; const float* ln2_b = (const float*)d_in[22];
  const float* Wi = (const float*)d_in[23];  const float* bi = (const float*)d_in[24];
  const float* ni_g = (const float*)d_in[25]; const float* ni_b = (const float*)d_in[26];
  const float* conv_a_w = (const float*)d_in[27];
  const float* conv_e_w = (const float*)d_in[28];
  const float* Wout = (const float*)d_in[29];
  const float* bout = (const float*)d_in[30];
  float* xf = (float*)d_ws;

  small_net_kernel<<<1, 256, 0, stream>>>(pos_a, ix_a, pos_ix, atom_ix, rpos_w,
      emb_w, emb_b, Wq, bq, Wk, bk, Wv, bv, Wo, bo, W1, b1, W2, b2,
      ln1_g, ln1_b, ln2_g, ln2_b, Wi, bi, ni_g, ni_b, conv_a_w, conv_e_w, xf);

  QCS cs;
  int n_e = in_sizes[2];
  for (int q = 0; q < QN; q++) {
    float hf = (q < n_e && (q % 2 == 0)) ? (float)M_PI : 0.0f;
    cs.c[q] = cosf(0.5f * hf);
    cs.s[q] = sinf(0.5f * hf);
  }

  int n = out_size;
  int blocks = (n + 255) / 256;
  psi_kernel<<<blocks, 256, 0, stream>>>(Wout, bout, xf, (float*)d_out, cs, n);
}

// Round 4
// 483.612 us; speedup vs baseline: 1.0428x; 1.0428x over previous
//
#include <hip/hip_runtime.h>
#include <math.h>

#define NE 22   // electrons
#define NA 11   // atoms
#define HD 8    // HID
#define H2 16   // 2*HID
#define QN 22   // QNUM
#define NL 6    // layers
#define CPAD 12 // atom conv position slots (11 + 1 pad)
#define CSTR 17 // conv row stride in floats (breaks pow2 bank pattern)

struct QCS { float c[QN]; float s[QN]; };

// wave-uniform broadcast (lane idx compile-time-uniform across wave)
#define RL(v, l) __uint_as_float(__builtin_amdgcn_readlane(__float_as_uint(v), (l)))

__device__ __forceinline__ float block_reduce_sum(float v, float* red, int tid) {
  red[tid] = v;
  __syncthreads();
  for (int off = 128; off > 0; off >>= 1) {
    if (tid < off) red[tid] += red[tid + off];
    __syncthreads();
  }
  float s = red[0];
  __syncthreads();
  return s;
}

__device__ __forceinline__ void ln_vec(const float* x, int n, const float* __restrict__ g,
                                       const float* __restrict__ bb, float* o) {
  float m = 0.f;
  for (int i = 0; i < n; i++) m += x[i];
  m /= (float)n;
  float v = 0.f;
  for (int i = 0; i < n; i++) { float d = x[i] - m; v += d * d; }
  v /= (float)n;
  float is = 1.0f / sqrtf(v + 1e-5f);
  for (int i = 0; i < n; i++) o[i] = (x[i] - m) * is * g[i] + bb[i];
}

// ============ K2: per-electron transformer, 22 blocks x 128 threads ============
// thread = (a = tid>>3, h = tid&7); active when a < NA. All weights in registers
// (each thread loads only the contiguous rows it needs -> float4, no broadcast).
__global__ __launch_bounds__(128, 1) void layers_kernel(
    const float* __restrict__ pos_a, const int* __restrict__ ix_a,
    const int* __restrict__ pos_ix, const int* __restrict__ atom_ix,
    const float* __restrict__ rpos_w, const float* __restrict__ emb_w,
    const float* __restrict__ emb_b,
    const float* __restrict__ Wq, const float* __restrict__ bq,
    const float* __restrict__ Wk, const float* __restrict__ bk,
    const float* __restrict__ Wv, const float* __restrict__ bv,
    const float* __restrict__ Wo, const float* __restrict__ bo,
    const float* __restrict__ W1, const float* __restrict__ b1,
    const float* __restrict__ W2, const float* __restrict__ b2,
    const float* __restrict__ ln1_g, const float* __restrict__ ln1_b,
    const float* __restrict__ ln2_g, const float* __restrict__ ln2_b,
    float* __restrict__ seq_out, float* __restrict__ rae_out)
{
  const int e = blockIdx.x;
  const int tid = threadIdx.x;
  const int a = tid >> 3;
  const int h = tid & 7;
  const bool act = (a < NA);

  __shared__ __align__(16) float sseq[NA][HD];
  __shared__ __align__(16) float sx[NA][HD];
  __shared__ __align__(16) float sq_[NA][HD];   // q; later xr / xr2
  __shared__ __align__(16) float sk_[NA][HD];   // k; later xn
  __shared__ __align__(16) float sv_[NA][HD];
  __shared__ __align__(16) float sav[NA][HD];
  __shared__ float ss[NA][12];
  __shared__ __align__(16) float sh_[NA][32];

  // ---- embedding ----
  float amp_a = 0.f;
  if (act) {
    amp_a = (float)ix_a[a];
    int p = pos_ix[e], am = atom_ix[e];
    float d0 = rpos_w[p*3+0] + pos_a[am*3+0] - pos_a[a*3+0];
    float d1 = rpos_w[p*3+1] + pos_a[am*3+1] - pos_a[a*3+1];
    float d2 = rpos_w[p*3+2] + pos_a[am*3+2] - pos_a[a*3+2];
    float rae = sqrtf(d0*d0 + d1*d1 + d2*d2);
    float s = emb_b[h] + d0*emb_w[h*4+0] + d1*emb_w[h*4+1]
            + d2*emb_w[h*4+2] + rae*emb_w[h*4+3];
    sseq[a][h] = s;
    if (h == 0) rae_out[e*NA + a] = rae;
  }
  __syncthreads();

  const float iscale = 0.35355339059327373f;  // 1/sqrt(8)
  for (int l = 0; l < NL; l++) {
    // per-thread weight rows (contiguous -> float4 loads, all independent)
    float wq[8], wk[8], wv[8], wo[8], w1v[4][8], w2v[32];
    {
      const float4* q4 = (const float4*)(Wq + l*64 + h*8);
      float4 t0 = q4[0], t1 = q4[1];
      wq[0]=t0.x; wq[1]=t0.y; wq[2]=t0.z; wq[3]=t0.w; wq[4]=t1.x; wq[5]=t1.y; wq[6]=t1.z; wq[7]=t1.w;
      const float4* k4 = (const float4*)(Wk + l*64 + h*8);
      t0 = k4[0]; t1 = k4[1];
      wk[0]=t0.x; wk[1]=t0.y; wk[2]=t0.z; wk[3]=t0.w; wk[4]=t1.x; wk[5]=t1.y; wk[6]=t1.z; wk[7]=t1.w;
      const float4* v4 = (const float4*)(Wv + l*64 + h*8);
      t0 = v4[0]; t1 = v4[1];
      wv[0]=t0.x; wv[1]=t0.y; wv[2]=t0.z; wv[3]=t0.w; wv[4]=t1.x; wv[5]=t1.y; wv[6]=t1.z; wv[7]=t1.w;
      const float4* o4 = (const float4*)(Wo + l*64 + h*8);
      t0 = o4[0]; t1 = o4[1];
      wo[0]=t0.x; wo[1]=t0.y; wo[2]=t0.z; wo[3]=t0.w; wo[4]=t1.x; wo[5]=t1.y; wo[6]=t1.z; wo[7]=t1.w;
      #pragma unroll
      for (int j = 0; j < 4; j++) {
        const float4* w14 = (const float4*)(W1 + l*256 + (j*8 + h)*8);
        float4 u0 = w14[0], u1 = w14[1];
        w1v[j][0]=u0.x; w1v[j][1]=u0.y; w1v[j][2]=u0.z; w1v[j][3]=u0.w;
        w1v[j][4]=u1.x; w1v[j][5]=u1.y; w1v[j][6]=u1.z; w1v[j][7]=u1.w;
      }
      const float4* w24 = (const float4*)(W2 + l*256 + h*32);
      #pragma unroll
      for (int j = 0; j < 8; j++) {
        float4 u = w24[j];
        w2v[j*4+0]=u.x; w2v[j*4+1]=u.y; w2v[j*4+2]=u.z; w2v[j*4+3]=u.w;
      }
    }
    float bqv = bq[l*8+h], bkv = bk[l*8+h], bvv = bv[l*8+h], bov = bo[l*8+h];
    float b1v[4];
    #pragma unroll
    for (int j = 0; j < 4; j++) b1v[j] = b1[l*32 + j*8 + h];
    float b2v = b2[l*8+h];
    float g1 = ln1_g[l*8+h], be1 = ln1_b[l*8+h];
    float g2 = ln2_g[l*8+h], be2 = ln2_b[l*8+h];

    // x = amp * seq
    float xah = 0.f;
    if (act) { xah = amp_a * sseq[a][h]; sx[a][h] = xah; }
    __syncthreads();

    // qkv
    if (act) {
      float xr[8];
      float4 r0 = *(const float4*)&sx[a][0];
      float4 r1 = *(const float4*)&sx[a][4];
      xr[0]=r0.x; xr[1]=r0.y; xr[2]=r0.z; xr[3]=r0.w; xr[4]=r1.x; xr[5]=r1.y; xr[6]=r1.z; xr[7]=r1.w;
      float q_ = bqv, k_ = bkv, v_ = bvv;
      #pragma unroll
      for (int h2 = 0; h2 < 8; h2++) {
        q_ += xr[h2]*wq[h2];
        k_ += xr[h2]*wk[h2];
        v_ += xr[h2]*wv[h2];
      }
      sq_[a][h] = q_; sk_[a][h] = k_; sv_[a][h] = v_;
    }
    __syncthreads();

    // scores: thread (a,h) does ka=h; h<3 also ka=8+h
    if (act) {
      float4 q0 = *(const float4*)&sq_[a][0];
      float4 q1 = *(const float4*)&sq_[a][4];
      {
        int ka = h;
        float4 k0 = *(const float4*)&sk_[ka][0];
        float4 k1 = *(const float4*)&sk_[ka][4];
        ss[a][ka] = iscale * (q0.x*k0.x + q0.y*k0.y + q0.z*k0.z + q0.w*k0.w
                            + q1.x*k1.x + q1.y*k1.y + q1.z*k1.z + q1.w*k1.w);
      }
      if (h < 3) {
        int ka = 8 + h;
        float4 k0 = *(const float4*)&sk_[ka][0];
        float4 k1 = *(const float4*)&sk_[ka][4];
        ss[a][ka] = iscale * (q0.x*k0.x + q0.y*k0.y + q0.z*k0.z + q0.w*k0.w
                            + q1.x*k1.x + q1.y*k1.y + q1.z*k1.z + q1.w*k1.w);
      }
    }
    __syncthreads();

    // softmax (redundant per thread of row a) + AV for own h
    float avh = 0.f;
    if (act) {
      float sc[NA], mx = -1e30f;
      #pragma unroll
      for (int ka = 0; ka < NA; ka++) { sc[ka] = ss[a][ka]; mx = fmaxf(mx, sc[ka]); }
      float den = 0.f;
      #pragma unroll
      for (int ka = 0; ka < NA; ka++) { sc[ka] = expf(sc[ka] - mx); den += sc[ka]; }
      float inv_den = 1.0f / den;
      #pragma unroll
      for (int ka = 0; ka < NA; ka++) avh += sc[ka] * sv_[ka][h];
      avh *= inv_den;
      sav[a][h] = avh;
    }
    __syncthreads();

    // O-proj + residual -> sq_ holds xr
    if (act) {
      float av[8];
      float4 r0 = *(const float4*)&sav[a][0];
      float4 r1 = *(const float4*)&sav[a][4];
      av[0]=r0.x; av[1]=r0.y; av[2]=r0.z; av[3]=r0.w; av[4]=r1.x; av[5]=r1.y; av[6]=r1.z; av[7]=r1.w;
      float t = bov;
      #pragma unroll
      for (int h2 = 0; h2 < 8; h2++) t += av[h2]*wo[h2];
      sq_[a][h] = xah + t;
    }
    __syncthreads();

    // LN1 (each thread produces its own element) -> sk_ holds xn
    float xnh = 0.f;
    if (act) {
      float4 r0 = *(const float4*)&sq_[a][0];
      float4 r1 = *(const float4*)&sq_[a][4];
      float m = (r0.x+r0.y+r0.z+r0.w+r1.x+r1.y+r1.z+r1.w) * 0.125f;
      float d, v = 0.f;
      d=r0.x-m; v+=d*d; d=r0.y-m; v+=d*d; d=r0.z-m; v+=d*d; d=r0.w-m; v+=d*d;
      d=r1.x-m; v+=d*d; d=r1.y-m; v+=d*d; d=r1.z-m; v+=d*d; d=r1.w-m; v+=d*d;
      v *= 0.125f;
      float is = 1.0f / sqrtf(v + 1e-5f);
      float own = (h<4) ? (&r0.x)[h] : (&r1.x)[h-4];
      xnh = (own - m) * is * g1 + be1;
      sk_[a][h] = xnh;
    }
    __syncthreads();

    // FFN hidden: thread handles o = j*8+h
    if (act) {
      float xn[8];
      float4 r0 = *(const float4*)&sk_[a][0];
      float4 r1 = *(const float4*)&sk_[a][4];
      xn[0]=r0.x; xn[1]=r0.y; xn[2]=r0.z; xn[3]=r0.w; xn[4]=r1.x; xn[5]=r1.y; xn[6]=r1.z; xn[7]=r1.w;
      #pragma unroll
      for (int j = 0; j < 4; j++) {
        float t = b1v[j];
        #pragma unroll
        for (int h2 = 0; h2 < 8; h2++) t += xn[h2]*w1v[j][h2];
        sh_[a][j*8+h] = fmaxf(t, 0.f);
      }
    }
    __syncthreads();

    // FFN out for own h + residual -> sq_ holds xr2
    if (act) {
      float f2 = b2v;
      #pragma unroll
      for (int j = 0; j < 8; j++) {
        float4 hv = *(const float4*)&sh_[a][j*4];
        f2 += hv.x*w2v[j*4+0] + hv.y*w2v[j*4+1] + hv.z*w2v[j*4+2] + hv.w*w2v[j*4+3];
      }
      sq_[a][h] = xnh + f2;
    }
    __syncthreads();

    // LN2 -> sseq
    if (act) {
      float4 r0 = *(const float4*)&sq_[a][0];
      float4 r1 = *(const float4*)&sq_[a][4];
      float m = (r0.x+r0.y+r0.z+r0.w+r1.x+r1.y+r1.z+r1.w) * 0.125f;
      float d, v = 0.f;
      d=r0.x-m; v+=d*d; d=r0.y-m; v+=d*d; d=r0.z-m; v+=d*d; d=r0.w-m; v+=d*d;
      d=r1.x-m; v+=d*d; d=r1.y-m; v+=d*d; d=r1.z-m; v+=d*d; d=r1.w-m; v+=d*d;
      v *= 0.125f;
      float is = 1.0f / sqrtf(v + 1e-5f);
      float own = (h<4) ? (&r0.x)[h] : (&r1.x)[h-4];
      sseq[a][h] = (own - m) * is * g2 + be2;
    }
    __syncthreads();
  }

  if (act) seq_out[e*NA*HD + a*HD + h] = sseq[a][h];
}

// ============ K3: tail (r-stats, exp, Wi, conv pyramids) — 1 block x 256 ============
__global__ __launch_bounds__(256) void tail_kernel(
    const int* __restrict__ ix_a, const float* __restrict__ emb_w,
    const float* __restrict__ Wi, const float* __restrict__ bi,
    const float* __restrict__ ni_g, const float* __restrict__ ni_b,
    const float* __restrict__ conv_a_w, const float* __restrict__ conv_e_w,
    const float* __restrict__ seq_ws, const float* __restrict__ rae_ws,
    float* __restrict__ xf_out)
{
  const int tid = threadIdx.x;
  const int lane = tid & 63;
  const int b = tid / NA;
  const int a = tid % NA;
  const bool act = (tid < NE * NA);

  __shared__ __align__(16) float s_seq[NE][NA][HD];
  __shared__ float s_amp[NA];
  __shared__ float s_er[NE][NA];
  __shared__ float s_red[256];
  __shared__ float s_scal[8];     // 0: amp_ae, 1: bias_ae, 4: amp_r2
  __shared__ float s_aeinv[HD];
  __shared__ float convA[NE * CPAD * CSTR];
  __shared__ float convB[NE * CPAD * CSTR];
  __shared__ float s_y[NE][H2];
  __shared__ float s_ampr[NE];
  __shared__ float s_eA[24 * CSTR];
  __shared__ float s_eB[24 * CSTR];
  __shared__ float s_y2[H2];
  __shared__ float s_cewt[32 * H2]; // conv_e_w transposed

  // lane-distributed weights for uniform readlane broadcast
  float cwr[8], wir[2];
  #pragma unroll
  for (int j = 0; j < 8; j++) cwr[j] = conv_a_w[j * 64 + lane];
  #pragma unroll
  for (int j = 0; j < 2; j++) wir[j] = Wi[j * 64 + lane];

  for (int s = tid; s < 512; s += 256) {
    int o = s >> 5, i = (s >> 1) & 15, k = s & 1;
    s_cewt[(i * 2 + k) * 16 + o] = conv_e_w[s];
  }
  // load seq from ws (484 float4s)
  for (int i = tid; i < NE*NA*HD/4; i += 256)
    ((float4*)s_seq)[i] = ((const float4*)seq_ws)[i];
  if (tid < NA) s_amp[tid] = (float)ix_a[tid];
  float rae = act ? rae_ws[tid] : 0.f;
  __syncthreads();

  // amp_ae / bias_ae
  {
    float sum = block_reduce_sum(act ? rae : 0.f, s_red, tid);
    float mean = sum / (float)(NE * NA);
    float d = act ? (rae - mean) : 0.f;
    float ss = block_reduce_sum(d * d, s_red, tid);
    if (tid == 0) { s_scal[0] = sqrtf(ss / (float)(NE * NA - 1)); s_scal[1] = mean; }
  }
  __syncthreads();

  // ae_inv last row (double Gauss-Jordan on one thread)
  if (tid == 0) {
    double M[4][8];
    for (int i = 0; i < 4; i++)
      for (int j = 0; j < 4; j++) {
        double s = 0.0;
        for (int h = 0; h < HD; h++) s += (double)emb_w[h * 4 + i] * (double)emb_w[h * 4 + j];
        M[i][j] = s;
        M[i][4 + j] = (i == j) ? 1.0 : 0.0;
      }
    for (int c = 0; c < 4; c++) {
      int piv = c;
      for (int r2 = c + 1; r2 < 4; r2++) if (fabs(M[r2][c]) > fabs(M[piv][c])) piv = r2;
      if (piv != c) for (int j = 0; j < 8; j++) { double t = M[c][j]; M[c][j] = M[piv][j]; M[piv][j] = t; }
      double dd = M[c][c];
      for (int j = 0; j < 8; j++) M[c][j] /= dd;
      for (int r2 = 0; r2 < 4; r2++) if (r2 != c) {
        double f = M[r2][c];
        for (int j = 0; j < 8; j++) M[r2][j] -= f * M[c][j];
      }
    }
    for (int h = 0; h < HD; h++) {
      double s = 0.0;
      for (int j = 0; j < 4; j++) s += M[3][4 + j] * (double)emb_w[h * 4 + j];
      s_aeinv[h] = (float)s;
    }
  }
  __syncthreads();

  // r projection + normalization + exp(-r)
  float rv = 0.f;
  if (act) {
    #pragma unroll
    for (int h = 0; h < HD; h++) rv += s_aeinv[h] * s_seq[b][a][h];
  }
  {
    float sum = block_reduce_sum(act ? rv : 0.f, s_red, tid);
    float rm = sum / (float)(NE * NA);
    float d = act ? (rv - rm) : 0.f;
    float ss = block_reduce_sum(d * d, s_red, tid);
    float rs = sqrtf(ss / (float)(NE * NA - 1));
    if (act) {
      float rr = s_scal[0] * (rv - rm) / rs + s_scal[1];
      s_er[b][a] = expf(-rr);
    }
  }
  __syncthreads();

  // Wi projection into conv buffer [bb][pos][chan]
  if (act) {
    float e2 = s_er[b][a] * s_amp[a];
    float4 sq0 = *(const float4*)&s_seq[b][a][0];
    float4 sq1 = *(const float4*)&s_seq[b][a][4];
    float tv[HD] = { e2*sq0.x, e2*sq0.y, e2*sq0.z, e2*sq0.w,
                     e2*sq1.x, e2*sq1.y, e2*sq1.z, e2*sq1.w };
    #pragma unroll
    for (int o = 0; o < H2; o++) {
      float s = bi[o];
      #pragma unroll
      for (int h = 0; h < HD; h++) s += tv[h] * RL(wir[(o * 8 + h) >> 6], (o * 8 + h) & 63);
      convA[(b * CPAD + a) * CSTR + o] = s;
    }
  }
  for (int z = tid; z < NE * H2; z += 256)
    convA[((z >> 4) * CPAD + 11) * CSTR + (z & 15)] = 0.f;
  __syncthreads();

  // y (mean over atoms), amp_r
  for (int idx = tid; idx < NE * H2; idx += 256) {
    int bb = idx >> 4, o = idx & 15;
    float s = 0.f;
    for (int a2 = 0; a2 < NA; a2++) s += convA[(bb * CPAD + a2) * CSTR + o];
    s_y[bb][o] = s / (float)NA;
  }
  if (tid < NE) {
    float s = 0.f;
    for (int a2 = 0; a2 < NA; a2++) s += s_er[tid][a2];
    s_ampr[tid] = s / (float)NA;
  }
  __syncthreads();

  // atom conv pyramid
  float* pin = convA;
  float* pout = convB;
  int L = NA;
  for (int it = 0; it < 6; it++) {
    int Lo = (L - 1) / 2 + 1;
    for (int pos = tid; pos < NE * Lo; pos += 256) {
      int bb = pos / Lo, j = pos - bb * Lo;
      const float* r0 = pin + (bb * CPAD + 2 * j) * CSTR;
      const float* r1 = r0 + CSTR;
      float x0[16], x1[16];
      #pragma unroll
      for (int i = 0; i < 16; i++) { x0[i] = r0[i]; x1[i] = r1[i]; }
      float* wrow = pout + (bb * CPAD + j) * CSTR;
      #pragma unroll
      for (int o = 0; o < 16; o++) {
        float acc = 0.f;
        #pragma unroll
        for (int i = 0; i < 16; i++) {
          acc += x0[i] * RL(cwr[((o * 16 + i) * 2) >> 6], ((o * 16 + i) * 2) & 63)
               + x1[i] * RL(cwr[((o * 16 + i) * 2 + 1) >> 6], ((o * 16 + i) * 2 + 1) & 63);
        }
        wrow[o] = acc;
      }
    }
    for (int z = tid; z < NE * H2; z += 256)
      pout[((z >> 4) * CPAD + Lo) * CSTR + (z & 15)] = 0.f;
    __syncthreads();
    float* t = pin; pin = pout; pout = t;
    L = Lo;
  }

  // per-electron LN, amp_r scaling -> electron buffer
  if (tid < NE) {
    float t[H2], oo[H2];
    #pragma unroll
    for (int o = 0; o < H2; o++) t[o] = s_y[tid][o] + pin[(tid * CPAD) * CSTR + o];
    ln_vec(t, H2, ni_g, ni_b, oo);
    float ar = s_ampr[tid];
    #pragma unroll
    for (int o = 0; o < H2; o++) s_eA[tid * CSTR + o] = ar * oo[o];
  }
  if (tid < H2) s_eA[NE * CSTR + tid] = 0.f;
  __syncthreads();
  if (tid < H2) {
    float s = 0.f;
    for (int bb = 0; bb < NE; bb++) s += s_eA[bb * CSTR + tid];
    s_y2[tid] = s / (float)NE;
  }
  if (tid == 0) {
    float s = 0.f;
    for (int bb = 0; bb < NE; bb++) s += s_ampr[bb];
    s_scal[4] = s / (float)NE;   // amp_r2
  }
  __syncthreads();

  // electron conv pyramid
  float* pinE = s_eA;
  float* poutE = s_eB;
  L = NE;
  for (int it = 0; it < 11; it++) {
    int Lo = (L - 1) / 2 + 1;
    for (int idx = tid; idx < Lo * H2; idx += 256) {
      int j = idx >> 4, o = idx & 15;
      const float* r0 = pinE + (2 * j) * CSTR;
      const float* r1 = r0 + CSTR;
      float acc = 0.f;
      #pragma unroll
      for (int i = 0; i < 16; i++)
        acc += r0[i] * s_cewt[(i * 2) * 16 + o] + r1[i] * s_cewt[(i * 2 + 1) * 16 + o];
      poutE[j * CSTR + o] = acc;
    }
    if (tid < H2) poutE[Lo * CSTR + tid] = 0.f;
    __syncthreads();
    float* t = pinE; pinE = poutE; poutE = t;
    L = Lo;
  }

  if (tid == 0) {
    float t[H2], oo[H2];
    for (int o = 0; o < H2; o++) t[o] = s_y2[o] + pinE[o];
    ln_vec(t, H2, ni_g, ni_b, oo);
    float a2 = s_scal[4];
    for (int o = 0; o < H2; o++) xf_out[o] = a2 * oo[o];
  }
}

// ============ psi: memory-bound output projection ============
__global__ __launch_bounds__(256) void psi_kernel(
    const float* __restrict__ Wout, const float* __restrict__ bout,
    const float* __restrict__ xf, float* __restrict__ out, QCS cs, int n)
{
  __shared__ float s_xf[H2];
  if (threadIdx.x < H2) s_xf[threadIdx.x] = xf[threadIdx.x];
  __syncthreads();
  int lane = threadIdx.x & 63;
  int waveBase = blockIdx.x * 256 + (threadIdx.x & ~63);
  if (waveBase >= n) return;
  const float4* W4 = (const float4*)Wout + (size_t)waveBase * 4;
  int q = lane & 3;
  float4 xq = make_float4(s_xf[q * 4], s_xf[q * 4 + 1], s_xf[q * 4 + 2], s_xf[q * 4 + 3]);
  #pragma unroll
  for (int j = 0; j < 4; j++) {
    float4 w = W4[j * 64 + lane];
    float p = w.x * xq.x + w.y * xq.y + w.z * xq.z + w.w * xq.w;
    p += __shfl_xor(p, 1, 64);
    p += __shfl_xor(p, 2, 64);
    if (q == 0) {
      int row = waveBase + j * 16 + (lane >> 2);
      float acc = bout[row] + p;
      unsigned int ii = (unsigned int)row;
      float pr = (float)(1 << (QN / 2));
      #pragma unroll
      for (int qb = 0; qb < QN; qb++)
        pr *= ((ii >> (QN - 1 - qb)) & 1u) ? cs.s[qb] : cs.c[qb];
      out[row] = acc + pr;
    }
  }
}

extern "C" void kernel_launch(void* const* d_in, const int* in_sizes, int n_in,
                              void* d_out, int out_size, void* d_ws, size_t ws_size,
                              hipStream_t stream) {
  const float* pos_a   = (const float*)d_in[0];
  const int*   ix_a    = (const int*)d_in[1];
  const int*   pos_ix  = (const int*)d_in[2];
  const int*   atom_ix = (const int*)d_in[3];
  const float* rpos_w  = (const float*)d_in[4];
  const float* emb_w   = (const float*)d_in[5];
  const float* emb_b   = (const float*)d_in[6];
  const float* Wq = (const float*)d_in[7];   const float* bq = (const float*)d_in[8];
  const float* Wk = (const float*)d_in[9];   const float* bk = (const float*)d_in[10];
  const float* Wv = (const float*)d_in[11];  const float* bv = (const float*)d_in[12];
  const float* Wo = (const float*)d_in[13];  const float* bo = (const float*)d_in[14];
  const float* W1 = (const float*)d_in[15];  const float* b1 = (const float*)d_in[16];
  const float* W2 = (const float*)d_in[17];  const float* b2 = (const float*)d_in[18];
  const float* ln1_g = (const float*)d_in[19]; const float* ln1_b = (const float*)d_in[20];
  const float* ln2_g = (const float*)d_in[21]; const float* ln2_b = (const float*)d_in[22];
  const float* Wi = (const float*)d_in[23];  const float* bi = (const float*)d_in[24];
  const float* ni_g = (const float*)d_in[25]; const float* ni_b = (const float*)d_in[26];
  const float* conv_a_w = (const float*)d_in[27];
  const float* conv_e_w = (const float*)d_in[28];
  const float* Wout = (const float*)d_in[29];
  const float* bout = (const float*)d_in[30];

  float* ws = (float*)d_ws;
  float* xf      = ws;          // [16]
  float* seq_ws  = ws + 64;     // [22*11*8]
  float* rae_ws  = ws + 64 + NE*NA*HD;  // [22*11]

  layers_kernel<<<NE, 128, 0, stream>>>(pos_a, ix_a, pos_ix, atom_ix, rpos_w,
      emb_w, emb_b, Wq, bq, Wk, bk, Wv, bv, Wo, bo, W1, b1, W2, b2,
      ln1_g, ln1_b, ln2_g, ln2_b, seq_ws, rae_ws);

  tail_kernel<<<1, 256, 0, stream>>>(ix_a, emb_w, Wi, bi, ni_g, ni_b,
      conv_a_w, conv_e_w, seq_ws, rae_ws, xf);

  QCS cs;
  int n_e = in_sizes[2];
  for (int q = 0; q < QN; q++) {
    float hf = (q < n_e && (q % 2 == 0)) ? (float)M_PI : 0.0f;
    cs.c[q] = cosf(0.5f * hf);
    cs.s[q] = sinf(0.5f * hf);
  }

  int n = out_size;
  int blocks = (n + 255) / 256;
  psi_kernel<<<blocks, 256, 0, stream>>>(Wout, bout, xf, (float*)d_out, cs, n);
}